// Round 9
// baseline (985.135 us; speedup 1.0000x reference)
//
#include <hip/hip_runtime.h>

typedef __attribute__((ext_vector_type(8))) short bf16x8;
typedef __attribute__((ext_vector_type(4))) float fx4;
typedef __attribute__((ext_vector_type(4))) unsigned short u16x4;
typedef __attribute__((ext_vector_type(8))) unsigned short u16x8;
typedef __attribute__((ext_vector_type(4))) unsigned int u32x4;

#define DEV static __device__ __forceinline__

DEV unsigned short f2bf(float f) {
  union { float f; unsigned u; } v; v.f = f;
  unsigned u = v.u;
  u += 0x7fffu + ((u >> 16) & 1u);
  return (unsigned short)(u >> 16);
}
DEV unsigned pk(float a, float b) { return (unsigned)f2bf(a) | ((unsigned)f2bf(b) << 16); }
DEV float sigm(float x) { return 1.f / (1.f + __expf(-x)); }

// coalesced 16B load bypassing (possibly stale) L1/L2, served at MALL.
DEV u32x4 load_coh16(const void* p) {
  u32x4 r;
  asm volatile("global_load_dwordx4 %0, %1, off sc0 sc1" : "=v"(r) : "v"(p));
  return r;
}

// async global->LDS 16B (m97 staging path)
typedef __attribute__((address_space(1))) const unsigned int guint;
typedef __attribute__((address_space(3))) unsigned int luint;
DEV void gload_lds16(const void* g, void* l) {
  __builtin_amdgcn_global_load_lds((guint*)g, (luint*)l, 16, 0, 0);
}

// ---------- dual embedding gather -> bf16, dst row r = t*32 + b ----------
__global__ void k_gather2(const float* __restrict__ embE, const int* __restrict__ tokE,
                          unsigned short* __restrict__ dstE,
                          const float* __restrict__ embC, const int* __restrict__ tokC,
                          unsigned short* __restrict__ dstC) {
  int bid = blockIdx.x;
  int r = bid & 2047;
  const float* emb = bid < 2048 ? embE : embC;
  const int* tok = bid < 2048 ? tokE : tokC;
  unsigned short* dst = bid < 2048 ? dstE : dstC;
  int t = r >> 5, b = r & 31;
  int token = tok[b * 64 + t];  // tok is [B=32][T=64]
  const fx4* srow = (const fx4*)(emb + (long)token * 1024);
  u16x4* drow = (u16x4*)(dst + (long)r * 1024);
  fx4 v = srow[threadIdx.x];
  u16x4 o = { f2bf(v[0]), f2bf(v[1]), f2bf(v[2]), f2bf(v[3]) };
  drow[threadIdx.x] = o;
}

// ---------- lengths + barrier zero ----------
__global__ void k_lengths(const int* __restrict__ mask, int* __restrict__ sel,
                          int* __restrict__ bar) {
  int t = threadIdx.x;
  for (int i = t; i < 4096; i += 256) bar[i] = 0;
  if (t < 32) {
    int s = 0;
    for (int k = 0; k < 64; ++k) s += mask[t * 64 + k];
    sel[t] = (s + 63) & 63;  // (sum-1) with jnp negative-index wrap
  }
}

// ---------- dual fp32 -> bf16 convert (WihE + WihD) ----------
__global__ void k_f2bf_dual(const float* __restrict__ s0, unsigned short* __restrict__ d0,
                            const float* __restrict__ s1, unsigned short* __restrict__ d1,
                            long n4) {
  const float* s = blockIdx.x < 1024 ? s0 : s1;
  unsigned short* d = blockIdx.x < 1024 ? d0 : d1;
  long base = (long)(blockIdx.x & 1023) * 256 + threadIdx.x;
  for (long i = base; i < n4; i += 1024 * 256) {
    fx4 v = ((const fx4*)s)[i];
    u16x4 o = { f2bf(v[0]), f2bf(v[1]), f2bf(v[2]), f2bf(v[3]) };
    ((u16x4*)d)[i] = o;
  }
}

// ============================================================================
// Persistent LSTM scan. 128 scan blocks x 512 threads, 1 block/CU (104 KB LDS).
// j0 XCD-swizzled; Whh fragments in registers; h staged to LDS via sc0/sc1
// coalesced loads; per-block monotone flags 128B apart.
// ============================================================================
#define SCAN_NBLK 128

template<int MODE>  // 0 = encoder (save h,c at t==sel[b]); 1 = decoder (emit hiddens)
__global__ __launch_bounds__(512) void k_scan(
    const float* __restrict__ Whh,        // [4096][1024] fp32
    const float* __restrict__ bhh,        // [4096]
    const float* __restrict__ xg,         // [64][32][4096] fp32
    const float* __restrict__ hinit,      // [32][1024] fp32 (h0 or hsel)
    const float* __restrict__ cinit,      // [32][1024] fp32 (c0 or csel)
    unsigned short* __restrict__ hbuf,    // [2][32][1024] bf16 double buffer
    const int* __restrict__ sel,
    float* __restrict__ hsel, float* __restrict__ csel,
    float* __restrict__ hid_out,          // [32][64][1024] fp32 (decoder)
    unsigned short* __restrict__ hid_bf,  // [2048][1024] bf16 (decoder, optional)
    int* __restrict__ bar,
    const float* __restrict__ wsrc,       // optional convert source
    unsigned short* __restrict__ wdst,    // optional convert dest
    long wn4) {
  int tid = threadIdx.x;
  int bid = blockIdx.x;
  if (bid >= SCAN_NBLK) {  // spare blocks: Wout convert on idle CUs, then exit
    long i = (long)(bid - SCAN_NBLK) * 512 + tid;
    long st = (long)(gridDim.x - SCAN_NBLK) * 512;
    for (; i < wn4; i += st) {
      fx4 v = ((const fx4*)wsrc)[i];
      u16x4 o = { f2bf(v[0]), f2bf(v[1]), f2bf(v[2]), f2bf(v[3]) };
      ((u16x4*)wdst)[i] = o;
    }
    return;
  }
  __shared__ __align__(16) unsigned short hlds[49152];  // 96 KB decl (64 used)
  __shared__ float gbuf[2][2][32][16];
  int j0 = ((bid & 7) * 16 + (bid >> 3)) * 8;  // XCD-contiguous j band
  int w = tid >> 6, lane = tid & 63;
  int mt = w & 1, nt = (w >> 1) & 1, kh = w >> 2;
  int fr = lane & 15, fg = lane >> 4;
  unsigned* hbU = (unsigned*)hbuf;
  constexpr int GBASE = MODE ? 64 : 0;

  // ---- one-time: this wave's Whh fragments into registers (fp32->bf16)
  bf16x8 breg[16];
  {
    int r = nt * 16 + fr;                    // local row: gate = r>>3, jj = r&7
    const float* wrow = Whh + ((long)((r >> 3) * 1024 + j0 + (r & 7)) << 10);
#pragma unroll
    for (int i = 0; i < 16; ++i) {
      int kc = (kh * 16 + i) * 4 + fg;
      fx4 lo = *(const fx4*)(wrow + kc * 8);
      fx4 hi = *(const fx4*)(wrow + kc * 8 + 4);
      bf16x8 o = { (short)f2bf(lo[0]), (short)f2bf(lo[1]), (short)f2bf(lo[2]), (short)f2bf(lo[3]),
                   (short)f2bf(hi[0]), (short)f2bf(hi[1]), (short)f2bf(hi[2]), (short)f2bf(hi[3]) };
      breg[i] = o;
    }
  }

  int b = (tid & 255) >> 3, jj = tid & 7, j = j0 + jj;
  float bh0 = 0.f, bh1 = 0.f, bh2 = 0.f, bh3 = 0.f, c_reg = 0.f;
  float x0 = 0.f, x1 = 0.f, x2 = 0.f, x3 = 0.f;
  int sel_b = -1;
  if (tid < 256) {
    bh0 = bhh[j]; bh1 = bhh[1024 + j]; bh2 = bhh[2048 + j]; bh3 = bhh[3072 + j];
    c_reg = cinit[b * 1024 + j];
    if (MODE == 0) sel_b = sel[b];
    const float* xp = xg + (long)b * 4096 + j;
    x0 = xp[0]; x1 = xp[1024]; x2 = xp[2048]; x3 = xp[3072];
  }

  for (int t = 0; t < 64; ++t) {
    // ---- stage h (64 KB bf16) into LDS ----
    if (t == 0) {
#pragma unroll
      for (int it = 0; it < 8; ++it) {
        int c = it * 512 + tid;
        const float* src = hinit + (long)c * 8;
        fx4 lo = *(const fx4*)src;
        fx4 hi = *(const fx4*)(src + 4);
        int row = c >> 7, kc = c & 127;
        u16x8 o = { f2bf(lo[0]), f2bf(lo[1]), f2bf(lo[2]), f2bf(lo[3]),
                    f2bf(hi[0]), f2bf(hi[1]), f2bf(hi[2]), f2bf(hi[3]) };
        *(u16x8*)&hlds[(row * 128 + (kc ^ (row & 31))) * 8] = o;
      }
    } else {
      const char* hsrc = (const char*)hbuf + (t & 1) * 65536;
      u32x4 hv[8];
#pragma unroll
      for (int it = 0; it < 8; ++it) {
        int c = it * 512 + tid;
        hv[it] = load_coh16(hsrc + (long)c * 16);
      }
      asm volatile("s_waitcnt vmcnt(0)" ::: "memory");
      __builtin_amdgcn_sched_barrier(0);
#pragma unroll
      for (int it = 0; it < 8; ++it) {
        int c = it * 512 + tid;
        int row = c >> 7, kc = c & 127;
        *(u16x8*)&hlds[(row * 128 + (kc ^ (row & 31))) * 8] = *(u16x8*)&hv[it];
      }
    }
    __syncthreads();

    // ---- gate GEMM: A-frags from hlds, B-frags from registers ----
    int arow = mt * 16 + fr;
    fx4 acca = {0.f, 0.f, 0.f, 0.f}, accb = {0.f, 0.f, 0.f, 0.f};
#pragma unroll
    for (int i = 0; i < 16; i += 2) {
      int kcA = (kh * 16 + i) * 4 + fg;
      int kcB = (kh * 16 + i + 1) * 4 + fg;
      bf16x8 a0 = *(const bf16x8*)&hlds[(arow * 128 + (kcA ^ (arow & 31))) * 8];
      bf16x8 a1 = *(const bf16x8*)&hlds[(arow * 128 + (kcB ^ (arow & 31))) * 8];
      acca = __builtin_amdgcn_mfma_f32_16x16x32_bf16(a0, breg[i], acca, 0, 0, 0);
      accb = __builtin_amdgcn_mfma_f32_16x16x32_bf16(a1, breg[i + 1], accb, 0, 0, 0);
    }
#pragma unroll
    for (int q = 0; q < 4; ++q)
      gbuf[kh][nt][mt * 16 + fg * 4 + q][fr] = acca[q] + accb[q];
    __syncthreads();

    // ---- gate nonlinearity + state update (256 threads: 32 b x 8 j) ----
    if (tid < 256) {
      float gi = gbuf[0][0][b][jj]     + gbuf[1][0][b][jj]     + bh0 + x0;
      float gf = gbuf[0][0][b][8 + jj] + gbuf[1][0][b][8 + jj] + bh1 + x1;
      float gg = gbuf[0][1][b][jj]     + gbuf[1][1][b][jj]     + bh2 + x2;
      float go = gbuf[0][1][b][8 + jj] + gbuf[1][1][b][8 + jj] + bh3 + x3;
      float c_new = sigm(gf) * c_reg + sigm(gi) * tanhf(gg);
      float h = sigm(go) * tanhf(c_new);
      c_reg = c_new;
      float hp = __shfl_xor(h, 1);
      if ((jj & 1) == 0) {
        unsigned val = pk(h, hp);
        __hip_atomic_store(&hbU[((t & 1) ^ 1) * 16384 + b * 512 + ((j0 + jj) >> 1)], val,
                           __ATOMIC_RELAXED, __HIP_MEMORY_SCOPE_AGENT);
      }
      if (MODE == 0) {
        if (t == sel_b) { hsel[b * 1024 + j] = h; csel[b * 1024 + j] = c_new; }
      } else {
        long o = ((long)b * 64 + t) * 1024 + j;
        hid_out[o] = h;
        if (hid_bf) hid_bf[o] = f2bf(h);
      }
    }

    if (t < 63) {
      float nx0 = 0.f, nx1 = 0.f, nx2 = 0.f, nx3 = 0.f;
      if (tid < 256) {
        const float* xp = xg + (long)(t + 1) * 131072 + (long)b * 4096 + j;
        nx0 = xp[0]; nx1 = xp[1024]; nx2 = xp[2048]; nx3 = xp[3072];
      }
      __syncthreads();  // drains vmcnt -> this block's h stores are MALL-visible
      if (w == 0) {
        if (lane == 0)
          __hip_atomic_store(&bar[bid * 32], GBASE + t + 1, __ATOMIC_RELAXED, __HIP_MEMORY_SCOPE_AGENT);
        int want = GBASE + t + 1;
        for (;;) {
          int v0 = __hip_atomic_load(&bar[lane * 32], __ATOMIC_RELAXED, __HIP_MEMORY_SCOPE_AGENT);
          int v1 = __hip_atomic_load(&bar[(64 + lane) * 32], __ATOMIC_RELAXED, __HIP_MEMORY_SCOPE_AGENT);
          if (__ballot(v0 >= want && v1 >= want) == 0xFFFFFFFFFFFFFFFFULL) break;
          __builtin_amdgcn_s_sleep(1);
        }
      }
      __syncthreads();
      x0 = nx0; x1 = nx1; x2 = nx2; x3 = nx3;
    }
  }
}

// ============================================================================
// Dual pre-gate GEMM (m97 + both-sides swizzle): blocks 0..511 -> set 0,
// 512..1023 -> set 1.
// ============================================================================
__global__ __launch_bounds__(256) void k_gemm_dual(
    const unsigned short* __restrict__ A0, const unsigned short* __restrict__ B0,
    const float* __restrict__ bias0, float* __restrict__ C0,
    const unsigned short* __restrict__ A1, const unsigned short* __restrict__ B1,
    const float* __restrict__ bias1, float* __restrict__ C1) {
  __shared__ __align__(16) unsigned short As[2][4096];
  __shared__ __align__(16) unsigned short Bs[2][4096];
  int lid = blockIdx.x;
  int half = lid >> 9, l = lid & 511;
  const unsigned short* A = half ? A1 : A0;
  const unsigned short* Bw = half ? B1 : B0;
  const float* bias = half ? bias1 : bias0;
  float* C = half ? C1 : C0;
  int swz = (l & 7) * 64 + (l >> 3);
  long m0 = (long)(swz & 15) * 128;
  long n0 = (long)(swz >> 4) * 128;
  int tid = threadIdx.x, lane = tid & 63, w = tid >> 6;
  int mw = (w & 1) * 64, nw = (w >> 1) * 64;
  int fr = lane & 15, fg = lane >> 4;
  fx4 acc[4][4] = {};
  int c0 = tid, c1 = tid + 256;
  int r0 = c0 >> 2, k0s = (c0 & 3) ^ ((r0 >> 1) & 3);
  int r1 = c1 >> 2, k1s = (c1 & 3) ^ ((r1 >> 1) & 3);
  const unsigned short* gA0 = A + (m0 + r0) * 1024 + k0s * 8;
  const unsigned short* gA1 = A + (m0 + r1) * 1024 + k1s * 8;
  const unsigned short* gB0 = Bw + (n0 + r0) * 1024 + k0s * 8;
  const unsigned short* gB1 = Bw + (n0 + r1) * 1024 + k1s * 8;
  auto stage = [&](int buf, int kt) {
    int k0 = kt * 32;
    gload_lds16(gA0 + k0, &As[buf][c0 * 8]);
    gload_lds16(gA1 + k0, &As[buf][c1 * 8]);
    gload_lds16(gB0 + k0, &Bs[buf][c0 * 8]);
    gload_lds16(gB1 + k0, &Bs[buf][c1 * 8]);
  };
  stage(0, 0);
  __syncthreads();
  for (int kt = 0; kt < 32; ++kt) {
    int cur = kt & 1;
    if (kt < 31) stage(cur ^ 1, kt + 1);
    bf16x8 af[4], bfr[4];
#pragma unroll
    for (int mi = 0; mi < 4; ++mi) {
      int row = mw + mi * 16 + fr;
      af[mi] = *(const bf16x8*)&As[cur][(row * 4 + (fg ^ ((row >> 1) & 3))) * 8];
    }
#pragma unroll
    for (int ni = 0; ni < 4; ++ni) {
      int row = nw + ni * 16 + fr;
      bfr[ni] = *(const bf16x8*)&Bs[cur][(row * 4 + (fg ^ ((row >> 1) & 3))) * 8];
    }
#pragma unroll
    for (int mi = 0; mi < 4; ++mi)
#pragma unroll
      for (int ni = 0; ni < 4; ++ni)
        acc[mi][ni] = __builtin_amdgcn_mfma_f32_16x16x32_bf16(af[mi], bfr[ni], acc[mi][ni], 0, 0, 0);
    __syncthreads();
  }
#pragma unroll
  for (int ni = 0; ni < 4; ++ni) {
    long n = n0 + nw + ni * 16 + fr;
    float bs = bias[n];
#pragma unroll
    for (int mi = 0; mi < 4; ++mi) {
      long rbase = m0 + mw + mi * 16 + fg * 4;
#pragma unroll
      for (int q = 0; q < 4; ++q)
        C[(rbase + q) * 4096 + n] = acc[mi][ni][q] + bs;
    }
  }
}

// ============================================================================
// Logits GEMM (m97 + both-sides swizzle) + BARRIER-FREE softmax partials.
// Each wave reduces its own 64x64 sub-tile with shfl_xor butterflies only
// (no extra __syncthreads, no LDS) and writes per-wave-half partials
// pm/ps[row*500 + nb*2 + (w>>1)].
// ============================================================================
__global__ __launch_bounds__(256) void k_gemm_sp(const unsigned short* __restrict__ A,
                                                 const unsigned short* __restrict__ Bw,
                                                 const float* __restrict__ bias,
                                                 float* __restrict__ C,
                                                 float* __restrict__ pm,
                                                 float* __restrict__ ps) {
  __shared__ __align__(16) unsigned short As[2][4096];
  __shared__ __align__(16) unsigned short Bs[2][4096];
  int lid = blockIdx.x;
  int swz = (lid & 7) * 500 + (lid >> 3);
  long m0 = (long)(swz & 15) * 128;
  long n0 = (long)(swz >> 4) * 128;
  int nb = swz >> 4;
  int tid = threadIdx.x, lane = tid & 63, w = tid >> 6;
  int mw = (w & 1) * 64, nw = (w >> 1) * 64;
  int fr = lane & 15, fg = lane >> 4;
  fx4 acc[4][4] = {};
  int c0 = tid, c1 = tid + 256;
  int r0 = c0 >> 2, k0s = (c0 & 3) ^ ((r0 >> 1) & 3);
  int r1 = c1 >> 2, k1s = (c1 & 3) ^ ((r1 >> 1) & 3);
  const unsigned short* gA0 = A + (m0 + r0) * 1024 + k0s * 8;
  const unsigned short* gA1 = A + (m0 + r1) * 1024 + k1s * 8;
  const unsigned short* gB0 = Bw + (n0 + r0) * 1024 + k0s * 8;
  const unsigned short* gB1 = Bw + (n0 + r1) * 1024 + k1s * 8;
  auto stage = [&](int buf, int kt) {
    int k0 = kt * 32;
    gload_lds16(gA0 + k0, &As[buf][c0 * 8]);
    gload_lds16(gA1 + k0, &As[buf][c1 * 8]);
    gload_lds16(gB0 + k0, &Bs[buf][c0 * 8]);
    gload_lds16(gB1 + k0, &Bs[buf][c1 * 8]);
  };
  stage(0, 0);
  __syncthreads();
  for (int kt = 0; kt < 32; ++kt) {
    int cur = kt & 1;
    if (kt < 31) stage(cur ^ 1, kt + 1);
    bf16x8 af[4], bfr[4];
#pragma unroll
    for (int mi = 0; mi < 4; ++mi) {
      int row = mw + mi * 16 + fr;
      af[mi] = *(const bf16x8*)&As[cur][(row * 4 + (fg ^ ((row >> 1) & 3))) * 8];
    }
#pragma unroll
    for (int ni = 0; ni < 4; ++ni) {
      int row = nw + ni * 16 + fr;
      bfr[ni] = *(const bf16x8*)&Bs[cur][(row * 4 + (fg ^ ((row >> 1) & 3))) * 8];
    }
#pragma unroll
    for (int mi = 0; mi < 4; ++mi)
#pragma unroll
      for (int ni = 0; ni < 4; ++ni)
        acc[mi][ni] = __builtin_amdgcn_mfma_f32_16x16x32_bf16(af[mi], bfr[ni], acc[mi][ni], 0, 0, 0);
    __syncthreads();
  }
  // bias into acc, then store C
#pragma unroll
  for (int ni = 0; ni < 4; ++ni) {
    long n = n0 + nw + ni * 16 + fr;
    float bs = bias[n];
#pragma unroll
    for (int mi = 0; mi < 4; ++mi) {
      long rbase = m0 + mw + mi * 16 + fg * 4;
#pragma unroll
      for (int q = 0; q < 4; ++q) {
        acc[mi][ni][q] += bs;
        C[(rbase + q) * 32000 + n] = acc[mi][ni][q];
      }
    }
  }
  if (!pm) return;
  // ---- barrier-free per-wave partials over this wave's 64 cols ----
  int half = w >> 1;  // which 64-col half of the 128-col block
  float rmax[4][4], rsum[4][4];
#pragma unroll
  for (int mi = 0; mi < 4; ++mi)
#pragma unroll
    for (int q = 0; q < 4; ++q)
      rmax[mi][q] = fmaxf(fmaxf(acc[mi][0][q], acc[mi][1][q]), fmaxf(acc[mi][2][q], acc[mi][3][q]));
#pragma unroll
  for (int off = 1; off < 16; off <<= 1)
#pragma unroll
    for (int mi = 0; mi < 4; ++mi)
#pragma unroll
      for (int q = 0; q < 4; ++q)
        rmax[mi][q] = fmaxf(rmax[mi][q], __shfl_xor(rmax[mi][q], off));
#pragma unroll
  for (int mi = 0; mi < 4; ++mi)
#pragma unroll
    for (int q = 0; q < 4; ++q)
      rsum[mi][q] = __expf(acc[mi][0][q] - rmax[mi][q]) + __expf(acc[mi][1][q] - rmax[mi][q]) +
                    __expf(acc[mi][2][q] - rmax[mi][q]) + __expf(acc[mi][3][q] - rmax[mi][q]);
#pragma unroll
  for (int off = 1; off < 16; off <<= 1)
#pragma unroll
    for (int mi = 0; mi < 4; ++mi)
#pragma unroll
      for (int q = 0; q < 4; ++q)
        rsum[mi][q] += __shfl_xor(rsum[mi][q], off);
  if (fr == 0) {
#pragma unroll
    for (int mi = 0; mi < 4; ++mi)
#pragma unroll
      for (int q = 0; q < 4; ++q) {
        long row = m0 + mw + mi * 16 + fg * 4 + q;
        pm[row * 500 + nb * 2 + half] = rmax[mi][q];
        ps[row * 500 + nb * 2 + half] = rsum[mi][q];
      }
  }
}

// ---------- combine partials -> lse[row] (one wave per row, 500 partials) ----------
__global__ __launch_bounds__(256) void k_lse(const float* __restrict__ pm,
                                             const float* __restrict__ ps,
                                             float* __restrict__ lse) {
  int w = threadIdx.x >> 6, lane = threadIdx.x & 63;
  int row = blockIdx.x * 4 + w;
  float m = -3.4e38f, s = 0.f;
  for (int i = lane; i < 500; i += 64) {
    float pmv = pm[(long)row * 500 + i], psv = ps[(long)row * 500 + i];
    float mn = fmaxf(m, pmv);
    s = s * __expf(m - mn) + psv * __expf(pmv - mn);
    m = mn;
  }
  for (int off = 32; off; off >>= 1) {
    float m2 = __shfl_xor(m, off), s2 = __shfl_xor(s, off);
    float mn = fmaxf(m, m2);
    s = s * __expf(m - mn) + s2 * __expf(m2 - mn);
    m = mn;
  }
  if (lane == 0) lse[row] = m + logf(s);
}

// ---------- normalize: logits -= lse[row] (single read+write pass) ----------
__global__ __launch_bounds__(256) void k_norm(float* __restrict__ logits,
                                              const float* __restrict__ lse) {
  long base = (long)blockIdx.x * 32000;
  float* row = logits + base;
  float l = lse[blockIdx.x];
  for (int i = threadIdx.x; i < 8000; i += 256) {
    fx4 v = ((const fx4*)row)[i];
    fx4 o = { v[0] - l, v[1] - l, v[2] - l, v[3] - l };
    ((fx4*)row)[i] = o;
  }
}

// ============================================================================
// Fallback GEMM (reg-staged, B may be fp32 converted in-register).
// ============================================================================
template<typename TA, typename TB>
__global__ __launch_bounds__(256) void k_gemm(const TA* __restrict__ A,
                                              const TB* __restrict__ Bw,
                                              const float* __restrict__ bias,
                                              float* __restrict__ C,
                                              int ldc, int q8) {
  __shared__ __align__(16) unsigned short As[2][4096];
  __shared__ __align__(16) unsigned short Bs[2][4096];
  int lid = blockIdx.x;
  int swz = (lid & 7) * q8 + (lid >> 3);
  long m0 = (long)(swz & 15) * 128;
  long n0 = (long)(swz >> 4) * 128;
  int tid = threadIdx.x, lane = tid & 63, w = tid >> 6;
  int mw = (w & 1) * 64, nw = (w >> 1) * 64;
  int fr = lane & 15, fg = lane >> 4;
  fx4 acc[4][4] = {};

  int crow[2], kc[2], phys[2];
#pragma unroll
  for (int u = 0; u < 2; ++u) {
    int c = tid + u * 256;
    crow[u] = c >> 2; kc[u] = c & 3;
    phys[u] = crow[u] * 4 + (kc[u] ^ ((crow[u] >> 1) & 3));
  }
  u32x4 ra[2], rb[2];
  auto loadOne = [&](const auto* P, long row, int u) -> u32x4 {
    long off = row * 1024 + kc[u] * 8;
    if constexpr (sizeof(*P) == 2) {
      return *(const u32x4*)(P + off);
    } else {
      fx4 lo = *(const fx4*)(P + off);
      fx4 hi = *(const fx4*)(P + off + 4);
      u32x4 r = { pk(lo[0], lo[1]), pk(lo[2], lo[3]), pk(hi[0], hi[1]), pk(hi[2], hi[3]) };
      return r;
    }
  };
  auto loadRegs = [&](int kt) {
#pragma unroll
    for (int u = 0; u < 2; ++u) {
      ra[u] = loadOne(A + (long)kt * 32, m0 + crow[u], u);
      rb[u] = loadOne(Bw + (long)kt * 32, n0 + crow[u], u);
    }
  };
  auto storeRegs = [&](int buf) {
#pragma unroll
    for (int u = 0; u < 2; ++u) {
      *(u32x4*)&As[buf][phys[u] * 8] = ra[u];
      *(u32x4*)&Bs[buf][phys[u] * 8] = rb[u];
    }
  };
  loadRegs(0);
  storeRegs(0);
  __syncthreads();
  for (int kt = 0; kt < 32; ++kt) {
    int cur = kt & 1;
    if (kt < 31) loadRegs(kt + 1);
    bf16x8 af[4], bf_[4];
#pragma unroll
    for (int mi = 0; mi < 4; ++mi) {
      int row = mw + mi * 16 + fr;
      af[mi] = *(const bf16x8*)&As[cur][(row * 4 + (fg ^ ((row >> 1) & 3))) * 8];
    }
#pragma unroll
    for (int ni = 0; ni < 4; ++ni) {
      int row = nw + ni * 16 + fr;
      bf_[ni] = *(const bf16x8*)&Bs[cur][(row * 4 + (fg ^ ((row >> 1) & 3))) * 8];
    }
#pragma unroll
    for (int mi = 0; mi < 4; ++mi)
#pragma unroll
      for (int ni = 0; ni < 4; ++ni)
        acc[mi][ni] = __builtin_amdgcn_mfma_f32_16x16x32_bf16(af[mi], bf_[ni], acc[mi][ni], 0, 0, 0);
    if (kt < 31) storeRegs((kt + 1) & 1);
    __syncthreads();
  }
#pragma unroll
  for (int ni = 0; ni < 4; ++ni) {
    long n = n0 + nw + ni * 16 + fr;
    float bs = bias[n];
#pragma unroll
    for (int mi = 0; mi < 4; ++mi) {
      long rbase = m0 + mw + mi * 16 + fg * 4;
#pragma unroll
      for (int q = 0; q < 4; ++q)
        C[(rbase + q) * ldc + n] = acc[mi][ni][q] + bs;
    }
  }
}

// ---------- fallback in-place row log-softmax ----------
__global__ __launch_bounds__(256) void k_logsoftmax(float* __restrict__ logits) {
  long base = (long)blockIdx.x * 32000;
  float* row = logits + base;
  int tid = threadIdx.x;
  __shared__ float redm[4], reds[4];
  float m = -3.4e38f, s = 0.f;
  for (int i = tid; i < 8000; i += 256) {
    fx4 v = ((const fx4*)row)[i];
    float cm = fmaxf(fmaxf(v[0], v[1]), fmaxf(v[2], v[3]));
    if (cm > m) { s *= __expf(m - cm); m = cm; }
    s += __expf(v[0] - m) + __expf(v[1] - m) + __expf(v[2] - m) + __expf(v[3] - m);
  }
  for (int o = 32; o; o >>= 1) {
    float m2 = __shfl_xor(m, o), s2 = __shfl_xor(s, o);
    float mn = fmaxf(m, m2);
    s = s * __expf(m - mn) + s2 * __expf(m2 - mn);
    m = mn;
  }
  if ((tid & 63) == 0) { redm[tid >> 6] = m; reds[tid >> 6] = s; }
  __syncthreads();
  float M = fmaxf(fmaxf(redm[0], redm[1]), fmaxf(redm[2], redm[3]));
  float S = reds[0] * __expf(redm[0] - M) + reds[1] * __expf(redm[1] - M) +
            reds[2] * __expf(redm[2] - M) + reds[3] * __expf(redm[3] - M);
  float lse = M + logf(S);
  for (int i = tid; i < 8000; i += 256) {
    fx4 v = ((const fx4*)row)[i];
    fx4 o = { v[0] - lse, v[1] - lse, v[2] - lse, v[3] - lse };
    ((fx4*)row)[i] = o;
  }
}

extern "C" void kernel_launch(void* const* d_in, const int* in_sizes, int n_in,
                              void* d_out, int out_size, void* d_ws, size_t ws_size,
                              hipStream_t stream) {
  const int*   x     = (const int*)d_in[0];
  const int*   xmask = (const int*)d_in[1];
  const int*   y     = (const int*)d_in[2];
  const float* h0    = (const float*)d_in[3];
  const float* c0    = (const float*)d_in[4];
  const float* embE  = (const float*)d_in[5];
  const float* embC  = (const float*)d_in[6];
  const float* WihE  = (const float*)d_in[7];
  const float* WhhE  = (const float*)d_in[8];
  const float* bihE  = (const float*)d_in[9];
  const float* bhhE  = (const float*)d_in[10];
  const float* WihD  = (const float*)d_in[11];
  const float* WhhD  = (const float*)d_in[12];
  const float* bihD  = (const float*)d_in[13];
  const float* bhhD  = (const float*)d_in[14];
  const float* Wout  = (const float*)d_in[15];
  const float* bout  = (const float*)d_in[16];

  float* out = (float*)d_out;
  float* decoded = out;                 // [2048][32000] final log-softmax
  float* hiddens = out + 65536000L;     // [32][64][1024] final hiddens

  // Pre-logits scratch inside the decoded region (fully consumed before the
  // logits GEMM overwrites it).
  float* xg_e = decoded;                                    // 8,388,608 f
  float* xg_d = decoded + 8388608L;                         // 8,388,608 f
  unsigned short* xe_bf   = (unsigned short*)(decoded + 16777216L);  // 2,097,152 us
  unsigned short* ye_bf   = xe_bf + 2097152L;                        // 2,097,152 us
  unsigned short* WihE_bf = ye_bf + 2097152L;                        // 4,194,304 us
  unsigned short* WihD_bf = WihE_bf + 4194304L;                      // 4,194,304 us
  char* sp = (char*)(WihD_bf + 4194304L);
  unsigned short* hbuf = (unsigned short*)sp; sp += 2 * 32768 * 2;   // 16B-aligned
  float* hsel = (float*)sp; sp += 32768 * 4;
  float* csel = (float*)sp; sp += 32768 * 4;
  int* sel = (int*)sp; sp += 256;
  int* bar = (int*)sp; sp += 16384;  // 128 flags, 128B apart (zeroed by k_lengths)

  // ws: bf16 hiddens (4MB) + bf16 Wout (65.5MB) + softmax partials (8.2MB)
  unsigned short* hid_bf  = (unsigned short*)d_ws;
  unsigned short* Wout_bf = hid_bf + 2097152L;
  float* pm  = (float*)(Wout_bf + 32768000L);
  float* psum = pm + 1024000L;
  float* lse = psum + 1024000L;
  size_t need1 = 2048L * 1024 * 2;
  size_t need2 = need1 + 32000L * 1024 * 2;
  size_t need3 = need2 + 1024000L * 8 + 8192;
  bool fast1 = ws_size >= need1;
  bool fast2 = ws_size >= need2;
  bool fast3 = ws_size >= need3;

  // gathers + lengths/bar-zero + Wih converts
  k_gather2<<<4096, 256, 0, stream>>>(embE, x, xe_bf, embC, y, ye_bf);
  k_lengths<<<1, 256, 0, stream>>>(xmask, sel, bar);
  k_f2bf_dual<<<2048, 256, 0, stream>>>(WihE, WihE_bf, WihD, WihD_bf, 1048576L);

  // both pre-gate GEMMs in one launch
  k_gemm_dual<<<1024, 256, 0, stream>>>(xe_bf, WihE_bf, bihE, xg_e,
                                        ye_bf, WihD_bf, bihD, xg_d);

  // encoder scan (+ Wout convert on spare CUs)
  k_scan<0><<<SCAN_NBLK + (fast2 ? 112 : 0), 512, 0, stream>>>(
      WhhE, bhhE, xg_e, h0, c0, hbuf, sel, hsel, csel, nullptr, nullptr, bar,
      Wout, Wout_bf, fast2 ? 8192000L : 0L);
  // decoder scan
  k_scan<1><<<SCAN_NBLK, 512, 0, stream>>>(
      WhhD, bhhD, xg_d, hsel, csel, hbuf, nullptr, nullptr, nullptr, hiddens,
      fast1 ? hid_bf : nullptr, bar, nullptr, nullptr, 0L);

  // logits GEMM + log-softmax, in place in d_out
  if (fast3) {
    k_gemm_sp<<<4000, 256, 0, stream>>>(hid_bf, Wout_bf, bout, decoded, pm, psum);
    k_lse<<<512, 256, 0, stream>>>(pm, psum, lse);
    k_norm<<<2048, 256, 0, stream>>>(decoded, lse);
  } else if (fast2) {
    k_gemm_sp<<<4000, 256, 0, stream>>>(hid_bf, Wout_bf, bout, decoded, nullptr, nullptr);
    k_logsoftmax<<<2048, 256, 0, stream>>>(decoded);
  } else if (fast1) {
    k_gemm<unsigned short, float><<<4000, 256, 0, stream>>>(hid_bf, Wout, bout, decoded, 32000, 500);
    k_logsoftmax<<<2048, 256, 0, stream>>>(decoded);
  } else {
    k_gemm<float, float><<<4000, 256, 0, stream>>>(hiddens, Wout, bout, decoded, 32000, 500);
    k_logsoftmax<<<2048, 256, 0, stream>>>(decoded);
  }
}

// Round 11
// 910.171 us; speedup vs baseline: 1.0824x; 1.0824x over previous
//
#include <hip/hip_runtime.h>

typedef __attribute__((ext_vector_type(8))) short bf16x8;
typedef __attribute__((ext_vector_type(4))) float fx4;
typedef __attribute__((ext_vector_type(4))) unsigned short u16x4;
typedef __attribute__((ext_vector_type(8))) unsigned short u16x8;
typedef __attribute__((ext_vector_type(4))) unsigned int u32x4;

#define DEV static __device__ __forceinline__

DEV unsigned short f2bf(float f) {
  union { float f; unsigned u; } v; v.f = f;
  unsigned u = v.u;
  u += 0x7fffu + ((u >> 16) & 1u);
  return (unsigned short)(u >> 16);
}
DEV unsigned pk(float a, float b) { return (unsigned)f2bf(a) | ((unsigned)f2bf(b) << 16); }
DEV float sigm(float x) { return 1.f / (1.f + __expf(-x)); }

// coalesced 16B load bypassing (possibly stale) L1/L2, served at MALL.
DEV u32x4 load_coh16(const void* p) {
  u32x4 r;
  asm volatile("global_load_dwordx4 %0, %1, off sc0 sc1" : "=v"(r) : "v"(p));
  return r;
}

// async global->LDS 16B (m97 staging path)
typedef __attribute__((address_space(1))) const unsigned int guint;
typedef __attribute__((address_space(3))) unsigned int luint;
DEV void gload_lds16(const void* g, void* l) {
  __builtin_amdgcn_global_load_lds((guint*)g, (luint*)l, 16, 0, 0);
}

// ---------- dual embedding gather -> bf16, dst row r = t*32 + b ----------
__global__ void k_gather2(const float* __restrict__ embE, const int* __restrict__ tokE,
                          unsigned short* __restrict__ dstE,
                          const float* __restrict__ embC, const int* __restrict__ tokC,
                          unsigned short* __restrict__ dstC) {
  int bid = blockIdx.x;
  int r = bid & 2047;
  const float* emb = bid < 2048 ? embE : embC;
  const int* tok = bid < 2048 ? tokE : tokC;
  unsigned short* dst = bid < 2048 ? dstE : dstC;
  int t = r >> 5, b = r & 31;
  int token = tok[b * 64 + t];  // tok is [B=32][T=64]
  const fx4* srow = (const fx4*)(emb + (long)token * 1024);
  u16x4* drow = (u16x4*)(dst + (long)r * 1024);
  fx4 v = srow[threadIdx.x];
  u16x4 o = { f2bf(v[0]), f2bf(v[1]), f2bf(v[2]), f2bf(v[3]) };
  drow[threadIdx.x] = o;
}

// ---------- lengths + barrier zero ----------
__global__ void k_lengths(const int* __restrict__ mask, int* __restrict__ sel,
                          int* __restrict__ bar) {
  int t = threadIdx.x;
  for (int i = t; i < 4096; i += 256) bar[i] = 0;
  if (t < 32) {
    int s = 0;
    for (int k = 0; k < 64; ++k) s += mask[t * 64 + k];
    sel[t] = (s + 63) & 63;  // (sum-1) with jnp negative-index wrap
  }
}

// ---------- dual fp32 -> bf16 convert (WihE + WihD) ----------
__global__ void k_f2bf_dual(const float* __restrict__ s0, unsigned short* __restrict__ d0,
                            const float* __restrict__ s1, unsigned short* __restrict__ d1,
                            long n4) {
  const float* s = blockIdx.x < 1024 ? s0 : s1;
  unsigned short* d = blockIdx.x < 1024 ? d0 : d1;
  long base = (long)(blockIdx.x & 1023) * 256 + threadIdx.x;
  for (long i = base; i < n4; i += 1024 * 256) {
    fx4 v = ((const fx4*)s)[i];
    u16x4 o = { f2bf(v[0]), f2bf(v[1]), f2bf(v[2]), f2bf(v[3]) };
    ((u16x4*)d)[i] = o;
  }
}

// ============================================================================
// Persistent LSTM scan. 128 scan blocks x 512 threads, 1 block/CU (104 KB LDS).
// j0 XCD-swizzled; Whh fragments in registers; h staged to LDS via sc0/sc1
// coalesced loads; per-block monotone flags 128B apart (enc gens 1..63,
// dec gens 65..127; bar zeroed once in k_lengths).
// Blocks >=128 (MODE 0 only): Wout fp32->bf16 convert on idle CUs, then exit
// (they retire — no co-residency requirement on them).
// ============================================================================
#define SCAN_NBLK 128

template<int MODE>  // 0 = encoder (save h,c at t==sel[b]); 1 = decoder (emit hiddens)
__global__ __launch_bounds__(512) void k_scan(
    const float* __restrict__ Whh,        // [4096][1024] fp32
    const float* __restrict__ bhh,        // [4096]
    const float* __restrict__ xg,         // [64][32][4096] fp32
    const float* __restrict__ hinit,      // [32][1024] fp32 (h0 or hsel)
    const float* __restrict__ cinit,      // [32][1024] fp32 (c0 or csel)
    unsigned short* __restrict__ hbuf,    // [2][32][1024] bf16 double buffer
    const int* __restrict__ sel,
    float* __restrict__ hsel, float* __restrict__ csel,
    float* __restrict__ hid_out,          // [32][64][1024] fp32 (decoder)
    unsigned short* __restrict__ hid_bf,  // [2048][1024] bf16 b-major (decoder)
    int* __restrict__ bar,
    const float* __restrict__ wsrc,       // MODE0: convert source
    unsigned short* __restrict__ wdst,    // MODE0: convert dest
    long wn4) {
  int tid = threadIdx.x;
  int bid = blockIdx.x;
  if (bid >= SCAN_NBLK) {  // spare blocks: Wout convert on idle CUs, then exit
    long i = (long)(bid - SCAN_NBLK) * 512 + tid;
    long st = (long)(gridDim.x - SCAN_NBLK) * 512;
    for (; i < wn4; i += st) {
      fx4 v = ((const fx4*)wsrc)[i];
      u16x4 o = { f2bf(v[0]), f2bf(v[1]), f2bf(v[2]), f2bf(v[3]) };
      ((u16x4*)wdst)[i] = o;
    }
    return;
  }
  __shared__ __align__(16) unsigned short hlds[49152];  // 96 KB decl (64 used)
  __shared__ float gbuf[2][2][32][16];
  int j0 = ((bid & 7) * 16 + (bid >> 3)) * 8;  // XCD-contiguous j band
  int w = tid >> 6, lane = tid & 63;
  int mt = w & 1, nt = (w >> 1) & 1, kh = w >> 2;
  int fr = lane & 15, fg = lane >> 4;
  unsigned* hbU = (unsigned*)hbuf;
  constexpr int GBASE = MODE ? 64 : 0;

  // ---- one-time: this wave's Whh fragments into registers (fp32->bf16)
  bf16x8 breg[16];
  {
    int r = nt * 16 + fr;                    // local row: gate = r>>3, jj = r&7
    const float* wrow = Whh + ((long)((r >> 3) * 1024 + j0 + (r & 7)) << 10);
#pragma unroll
    for (int i = 0; i < 16; ++i) {
      int kc = (kh * 16 + i) * 4 + fg;
      fx4 lo = *(const fx4*)(wrow + kc * 8);
      fx4 hi = *(const fx4*)(wrow + kc * 8 + 4);
      bf16x8 o = { (short)f2bf(lo[0]), (short)f2bf(lo[1]), (short)f2bf(lo[2]), (short)f2bf(lo[3]),
                   (short)f2bf(hi[0]), (short)f2bf(hi[1]), (short)f2bf(hi[2]), (short)f2bf(hi[3]) };
      breg[i] = o;
    }
  }

  int b = (tid & 255) >> 3, jj = tid & 7, j = j0 + jj;
  float bh0 = 0.f, bh1 = 0.f, bh2 = 0.f, bh3 = 0.f, c_reg = 0.f;
  float x0 = 0.f, x1 = 0.f, x2 = 0.f, x3 = 0.f;
  int sel_b = -1;
  if (tid < 256) {
    bh0 = bhh[j]; bh1 = bhh[1024 + j]; bh2 = bhh[2048 + j]; bh3 = bhh[3072 + j];
    c_reg = cinit[b * 1024 + j];
    if (MODE == 0) sel_b = sel[b];
    const float* xp = xg + (long)b * 4096 + j;
    x0 = xp[0]; x1 = xp[1024]; x2 = xp[2048]; x3 = xp[3072];
  }

  for (int t = 0; t < 64; ++t) {
    // ---- stage h (64 KB bf16) into LDS ----
    if (t == 0) {
#pragma unroll
      for (int it = 0; it < 8; ++it) {
        int c = it * 512 + tid;
        const float* src = hinit + (long)c * 8;
        fx4 lo = *(const fx4*)src;
        fx4 hi = *(const fx4*)(src + 4);
        int row = c >> 7, kc = c & 127;
        u16x8 o = { f2bf(lo[0]), f2bf(lo[1]), f2bf(lo[2]), f2bf(lo[3]),
                    f2bf(hi[0]), f2bf(hi[1]), f2bf(hi[2]), f2bf(hi[3]) };
        *(u16x8*)&hlds[(row * 128 + (kc ^ (row & 31))) * 8] = o;
      }
    } else {
      const char* hsrc = (const char*)hbuf + (t & 1) * 65536;
      u32x4 hv[8];
#pragma unroll
      for (int it = 0; it < 8; ++it) {
        int c = it * 512 + tid;
        hv[it] = load_coh16(hsrc + (long)c * 16);
      }
      asm volatile("s_waitcnt vmcnt(0)" ::: "memory");
      __builtin_amdgcn_sched_barrier(0);
#pragma unroll
      for (int it = 0; it < 8; ++it) {
        int c = it * 512 + tid;
        int row = c >> 7, kc = c & 127;
        *(u16x8*)&hlds[(row * 128 + (kc ^ (row & 31))) * 8] = *(u16x8*)&hv[it];
      }
    }
    __syncthreads();

    // ---- gate GEMM: A-frags from hlds, B-frags from registers ----
    int arow = mt * 16 + fr;
    fx4 acca = {0.f, 0.f, 0.f, 0.f}, accb = {0.f, 0.f, 0.f, 0.f};
#pragma unroll
    for (int i = 0; i < 16; i += 2) {
      int kcA = (kh * 16 + i) * 4 + fg;
      int kcB = (kh * 16 + i + 1) * 4 + fg;
      bf16x8 a0 = *(const bf16x8*)&hlds[(arow * 128 + (kcA ^ (arow & 31))) * 8];
      bf16x8 a1 = *(const bf16x8*)&hlds[(arow * 128 + (kcB ^ (arow & 31))) * 8];
      acca = __builtin_amdgcn_mfma_f32_16x16x32_bf16(a0, breg[i], acca, 0, 0, 0);
      accb = __builtin_amdgcn_mfma_f32_16x16x32_bf16(a1, breg[i + 1], accb, 0, 0, 0);
    }
#pragma unroll
    for (int q = 0; q < 4; ++q)
      gbuf[kh][nt][mt * 16 + fg * 4 + q][fr] = acca[q] + accb[q];
    __syncthreads();

    // ---- gate nonlinearity + state update (256 threads: 32 b x 8 j) ----
    if (tid < 256) {
      float gi = gbuf[0][0][b][jj]     + gbuf[1][0][b][jj]     + bh0 + x0;
      float gf = gbuf[0][0][b][8 + jj] + gbuf[1][0][b][8 + jj] + bh1 + x1;
      float gg = gbuf[0][1][b][jj]     + gbuf[1][1][b][jj]     + bh2 + x2;
      float go = gbuf[0][1][b][8 + jj] + gbuf[1][1][b][8 + jj] + bh3 + x3;
      float c_new = sigm(gf) * c_reg + sigm(gi) * tanhf(gg);
      float h = sigm(go) * tanhf(c_new);
      c_reg = c_new;
      float hp = __shfl_xor(h, 1);
      if ((jj & 1) == 0) {
        unsigned val = pk(h, hp);
        __hip_atomic_store(&hbU[((t & 1) ^ 1) * 16384 + b * 512 + ((j0 + jj) >> 1)], val,
                           __ATOMIC_RELAXED, __HIP_MEMORY_SCOPE_AGENT);
      }
      if (MODE == 0) {
        if (t == sel_b) { hsel[b * 1024 + j] = h; csel[b * 1024 + j] = c_new; }
      } else {
        long o = ((long)b * 64 + t) * 1024 + j;
        hid_out[o] = h;
        if (hid_bf) hid_bf[o] = f2bf(h);  // plain store; read next kernel
      }
    }

    if (t < 63) {
      float nx0 = 0.f, nx1 = 0.f, nx2 = 0.f, nx3 = 0.f;
      if (tid < 256) {
        const float* xp = xg + (long)(t + 1) * 131072 + (long)b * 4096 + j;
        nx0 = xp[0]; nx1 = xp[1024]; nx2 = xp[2048]; nx3 = xp[3072];
      }
      __syncthreads();  // drains vmcnt -> this block's h stores are MALL-visible
      if (w == 0) {
        if (lane == 0)
          __hip_atomic_store(&bar[bid * 32], GBASE + t + 1, __ATOMIC_RELAXED, __HIP_MEMORY_SCOPE_AGENT);
        int want = GBASE + t + 1;
        for (;;) {
          int v0 = __hip_atomic_load(&bar[lane * 32], __ATOMIC_RELAXED, __HIP_MEMORY_SCOPE_AGENT);
          int v1 = __hip_atomic_load(&bar[(64 + lane) * 32], __ATOMIC_RELAXED, __HIP_MEMORY_SCOPE_AGENT);
          if (__ballot(v0 >= want && v1 >= want) == 0xFFFFFFFFFFFFFFFFULL) break;
          __builtin_amdgcn_s_sleep(1);
        }
      }
      __syncthreads();
      x0 = nx0; x1 = nx1; x2 = nx2; x3 = nx3;
    }
  }
}

// ============================================================================
// Dual pre-gate GEMM (m97 + both-sides swizzle): blocks 0..511 -> set 0,
// 512..1023 -> set 1. (R7-R9 proven)
// ============================================================================
__global__ __launch_bounds__(256) void k_gemm_dual(
    const unsigned short* __restrict__ A0, const unsigned short* __restrict__ B0,
    const float* __restrict__ bias0, float* __restrict__ C0,
    const unsigned short* __restrict__ A1, const unsigned short* __restrict__ B1,
    const float* __restrict__ bias1, float* __restrict__ C1) {
  __shared__ __align__(16) unsigned short As[2][4096];
  __shared__ __align__(16) unsigned short Bs[2][4096];
  int lid = blockIdx.x;
  int half = lid >> 9, l = lid & 511;
  const unsigned short* A = half ? A1 : A0;
  const unsigned short* Bw = half ? B1 : B0;
  const float* bias = half ? bias1 : bias0;
  float* C = half ? C1 : C0;
  int swz = (l & 7) * 64 + (l >> 3);
  long m0 = (long)(swz & 15) * 128;
  long n0 = (long)(swz >> 4) * 128;
  int tid = threadIdx.x, lane = tid & 63, w = tid >> 6;
  int mw = (w & 1) * 64, nw = (w >> 1) * 64;
  int fr = lane & 15, fg = lane >> 4;
  fx4 acc[4][4] = {};
  int c0 = tid, c1 = tid + 256;
  int r0 = c0 >> 2, k0s = (c0 & 3) ^ ((r0 >> 1) & 3);
  int r1 = c1 >> 2, k1s = (c1 & 3) ^ ((r1 >> 1) & 3);
  const unsigned short* gA0 = A + (m0 + r0) * 1024 + k0s * 8;
  const unsigned short* gA1 = A + (m0 + r1) * 1024 + k1s * 8;
  const unsigned short* gB0 = Bw + (n0 + r0) * 1024 + k0s * 8;
  const unsigned short* gB1 = Bw + (n0 + r1) * 1024 + k1s * 8;
  auto stage = [&](int buf, int kt) {
    int k0 = kt * 32;
    gload_lds16(gA0 + k0, &As[buf][c0 * 8]);
    gload_lds16(gA1 + k0, &As[buf][c1 * 8]);
    gload_lds16(gB0 + k0, &Bs[buf][c0 * 8]);
    gload_lds16(gB1 + k0, &Bs[buf][c1 * 8]);
  };
  stage(0, 0);
  __syncthreads();
  for (int kt = 0; kt < 32; ++kt) {
    int cur = kt & 1;
    if (kt < 31) stage(cur ^ 1, kt + 1);
    bf16x8 af[4], bfr[4];
#pragma unroll
    for (int mi = 0; mi < 4; ++mi) {
      int row = mw + mi * 16 + fr;
      af[mi] = *(const bf16x8*)&As[cur][(row * 4 + (fg ^ ((row >> 1) & 3))) * 8];
    }
#pragma unroll
    for (int ni = 0; ni < 4; ++ni) {
      int row = nw + ni * 16 + fr;
      bfr[ni] = *(const bf16x8*)&Bs[cur][(row * 4 + (fg ^ ((row >> 1) & 3))) * 8];
    }
#pragma unroll
    for (int mi = 0; mi < 4; ++mi)
#pragma unroll
      for (int ni = 0; ni < 4; ++ni)
        acc[mi][ni] = __builtin_amdgcn_mfma_f32_16x16x32_bf16(af[mi], bfr[ni], acc[mi][ni], 0, 0, 0);
    __syncthreads();
  }
#pragma unroll
  for (int ni = 0; ni < 4; ++ni) {
    long n = n0 + nw + ni * 16 + fr;
    float bs = bias[n];
#pragma unroll
    for (int mi = 0; mi < 4; ++mi) {
      long rbase = m0 + mw + mi * 16 + fg * 4;
#pragma unroll
      for (int q = 0; q < 4; ++q)
        C[(rbase + q) * 4096 + n] = acc[mi][ni][q] + bs;
    }
  }
}

// ============================================================================
// Logits GEMM (m97 + both-sides swizzle, NO epilogue extras — R6-class).
// M=2048 N=32000 K=1024, grid 4000, q8=500.
// ============================================================================
__global__ __launch_bounds__(256) void k_gemm_bb(const unsigned short* __restrict__ A,
                                                 const unsigned short* __restrict__ Bw,
                                                 const float* __restrict__ bias,
                                                 float* __restrict__ C) {
  __shared__ __align__(16) unsigned short As[2][4096];
  __shared__ __align__(16) unsigned short Bs[2][4096];
  int lid = blockIdx.x;
  int swz = (lid & 7) * 500 + (lid >> 3);   // XCD-chunked (4000 % 8 == 0)
  long m0 = (long)(swz & 15) * 128;         // m inner -> B-panel L2 reuse
  long n0 = (long)(swz >> 4) * 128;
  int tid = threadIdx.x, lane = tid & 63, w = tid >> 6;
  int mw = (w & 1) * 64, nw = (w >> 1) * 64;
  int fr = lane & 15, fg = lane >> 4;
  fx4 acc[4][4] = {};
  int c0 = tid, c1 = tid + 256;
  int r0 = c0 >> 2, k0s = (c0 & 3) ^ ((r0 >> 1) & 3);
  int r1 = c1 >> 2, k1s = (c1 & 3) ^ ((r1 >> 1) & 3);
  const unsigned short* gA0 = A + (m0 + r0) * 1024 + k0s * 8;
  const unsigned short* gA1 = A + (m0 + r1) * 1024 + k1s * 8;
  const unsigned short* gB0 = Bw + (n0 + r0) * 1024 + k0s * 8;
  const unsigned short* gB1 = Bw + (n0 + r1) * 1024 + k1s * 8;
  auto stage = [&](int buf, int kt) {
    int k0 = kt * 32;
    gload_lds16(gA0 + k0, &As[buf][c0 * 8]);
    gload_lds16(gA1 + k0, &As[buf][c1 * 8]);
    gload_lds16(gB0 + k0, &Bs[buf][c0 * 8]);
    gload_lds16(gB1 + k0, &Bs[buf][c1 * 8]);
  };
  stage(0, 0);
  __syncthreads();
  for (int kt = 0; kt < 32; ++kt) {
    int cur = kt & 1;
    if (kt < 31) stage(cur ^ 1, kt + 1);
    bf16x8 af[4], bfr[4];
#pragma unroll
    for (int mi = 0; mi < 4; ++mi) {
      int row = mw + mi * 16 + fr;
      af[mi] = *(const bf16x8*)&As[cur][(row * 4 + (fg ^ ((row >> 1) & 3))) * 8];
    }
#pragma unroll
    for (int ni = 0; ni < 4; ++ni) {
      int row = nw + ni * 16 + fr;
      bfr[ni] = *(const bf16x8*)&Bs[cur][(row * 4 + (fg ^ ((row >> 1) & 3))) * 8];
    }
#pragma unroll
    for (int mi = 0; mi < 4; ++mi)
#pragma unroll
      for (int ni = 0; ni < 4; ++ni)
        acc[mi][ni] = __builtin_amdgcn_mfma_f32_16x16x32_bf16(af[mi], bfr[ni], acc[mi][ni], 0, 0, 0);
    __syncthreads();
  }
#pragma unroll
  for (int ni = 0; ni < 4; ++ni) {
    long n = n0 + nw + ni * 16 + fr;
    float bs = bias[n];
#pragma unroll
    for (int mi = 0; mi < 4; ++mi) {
      long rbase = m0 + mw + mi * 16 + fg * 4;
#pragma unroll
      for (int q = 0; q < 4; ++q)
        C[(rbase + q) * 32000 + n] = acc[mi][ni][q] + bs;
    }
  }
}

// ============================================================================
// Fallback GEMM (reg-staged, B may be fp32 converted in-register).
// ============================================================================
template<typename TA, typename TB>
__global__ __launch_bounds__(256) void k_gemm(const TA* __restrict__ A,
                                              const TB* __restrict__ Bw,
                                              const float* __restrict__ bias,
                                              float* __restrict__ C,
                                              int ldc, int q8) {
  __shared__ __align__(16) unsigned short As[2][4096];
  __shared__ __align__(16) unsigned short Bs[2][4096];
  int lid = blockIdx.x;
  int swz = (lid & 7) * q8 + (lid >> 3);
  long m0 = (long)(swz & 15) * 128;
  long n0 = (long)(swz >> 4) * 128;
  int tid = threadIdx.x, lane = tid & 63, w = tid >> 6;
  int mw = (w & 1) * 64, nw = (w >> 1) * 64;
  int fr = lane & 15, fg = lane >> 4;
  fx4 acc[4][4] = {};

  int crow[2], kc[2], phys[2];
#pragma unroll
  for (int u = 0; u < 2; ++u) {
    int c = tid + u * 256;
    crow[u] = c >> 2; kc[u] = c & 3;
    phys[u] = crow[u] * 4 + (kc[u] ^ ((crow[u] >> 1) & 3));
  }
  u32x4 ra[2], rb[2];
  auto loadOne = [&](const auto* P, long row, int u) -> u32x4 {
    long off = row * 1024 + kc[u] * 8;
    if constexpr (sizeof(*P) == 2) {
      return *(const u32x4*)(P + off);
    } else {
      fx4 lo = *(const fx4*)(P + off);
      fx4 hi = *(const fx4*)(P + off + 4);
      u32x4 r = { pk(lo[0], lo[1]), pk(lo[2], lo[3]), pk(hi[0], hi[1]), pk(hi[2], hi[3]) };
      return r;
    }
  };
  auto loadRegs = [&](int kt) {
#pragma unroll
    for (int u = 0; u < 2; ++u) {
      ra[u] = loadOne(A + (long)kt * 32, m0 + crow[u], u);
      rb[u] = loadOne(Bw + (long)kt * 32, n0 + crow[u], u);
    }
  };
  auto storeRegs = [&](int buf) {
#pragma unroll
    for (int u = 0; u < 2; ++u) {
      *(u32x4*)&As[buf][phys[u] * 8] = ra[u];
      *(u32x4*)&Bs[buf][phys[u] * 8] = rb[u];
    }
  };
  loadRegs(0);
  storeRegs(0);
  __syncthreads();
  for (int kt = 0; kt < 32; ++kt) {
    int cur = kt & 1;
    if (kt < 31) loadRegs(kt + 1);
    bf16x8 af[4], bf_[4];
#pragma unroll
    for (int mi = 0; mi < 4; ++mi) {
      int row = mw + mi * 16 + fr;
      af[mi] = *(const bf16x8*)&As[cur][(row * 4 + (fg ^ ((row >> 1) & 3))) * 8];
    }
#pragma unroll
    for (int ni = 0; ni < 4; ++ni) {
      int row = nw + ni * 16 + fr;
      bf_[ni] = *(const bf16x8*)&Bs[cur][(row * 4 + (fg ^ ((row >> 1) & 3))) * 8];
    }
#pragma unroll
    for (int mi = 0; mi < 4; ++mi)
#pragma unroll
      for (int ni = 0; ni < 4; ++ni)
        acc[mi][ni] = __builtin_amdgcn_mfma_f32_16x16x32_bf16(af[mi], bf_[ni], acc[mi][ni], 0, 0, 0);
    if (kt < 31) storeRegs((kt + 1) & 1);
    __syncthreads();
  }
#pragma unroll
  for (int ni = 0; ni < 4; ++ni) {
    long n = n0 + nw + ni * 16 + fr;
    float bs = bias[n];
#pragma unroll
    for (int mi = 0; mi < 4; ++mi) {
      long rbase = m0 + mw + mi * 16 + fg * 4;
#pragma unroll
      for (int q = 0; q < 4; ++q)
        C[(rbase + q) * ldc + n] = acc[mi][ni][q] + bs;
    }
  }
}

// ---------- in-place row log-softmax, online max+sum (single extra read) ----------
__global__ __launch_bounds__(256) void k_logsoftmax(float* __restrict__ logits) {
  long base = (long)blockIdx.x * 32000;
  float* row = logits + base;
  int tid = threadIdx.x;
  __shared__ float redm[4], reds[4];
  float m = -3.4e38f, s = 0.f;
  for (int i = tid; i < 8000; i += 256) {
    fx4 v = ((const fx4*)row)[i];
    float cm = fmaxf(fmaxf(v[0], v[1]), fmaxf(v[2], v[3]));
    if (cm > m) { s *= __expf(m - cm); m = cm; }
    s += __expf(v[0] - m) + __expf(v[1] - m) + __expf(v[2] - m) + __expf(v[3] - m);
  }
  for (int o = 32; o; o >>= 1) {
    float m2 = __shfl_xor(m, o), s2 = __shfl_xor(s, o);
    float mn = fmaxf(m, m2);
    s = s * __expf(m - mn) + s2 * __expf(m2 - mn);
    m = mn;
  }
  if ((tid & 63) == 0) { redm[tid >> 6] = m; reds[tid >> 6] = s; }
  __syncthreads();
  float M = fmaxf(fmaxf(redm[0], redm[1]), fmaxf(redm[2], redm[3]));
  float S = reds[0] * __expf(redm[0] - M) + reds[1] * __expf(redm[1] - M) +
            reds[2] * __expf(redm[2] - M) + reds[3] * __expf(redm[3] - M);
  float lse = M + logf(S);
  for (int i = tid; i < 8000; i += 256) {
    fx4 v = ((const fx4*)row)[i];
    fx4 o = { v[0] - lse, v[1] - lse, v[2] - lse, v[3] - lse };
    ((fx4*)row)[i] = o;
  }
}

extern "C" void kernel_launch(void* const* d_in, const int* in_sizes, int n_in,
                              void* d_out, int out_size, void* d_ws, size_t ws_size,
                              hipStream_t stream) {
  const int*   x     = (const int*)d_in[0];
  const int*   xmask = (const int*)d_in[1];
  const int*   y     = (const int*)d_in[2];
  const float* h0    = (const float*)d_in[3];
  const float* c0    = (const float*)d_in[4];
  const float* embE  = (const float*)d_in[5];
  const float* embC  = (const float*)d_in[6];
  const float* WihE  = (const float*)d_in[7];
  const float* WhhE  = (const float*)d_in[8];
  const float* bihE  = (const float*)d_in[9];
  const float* bhhE  = (const float*)d_in[10];
  const float* WihD  = (const float*)d_in[11];
  const float* WhhD  = (const float*)d_in[12];
  const float* bihD  = (const float*)d_in[13];
  const float* bhhD  = (const float*)d_in[14];
  const float* Wout  = (const float*)d_in[15];
  const float* bout  = (const float*)d_in[16];

  float* out = (float*)d_out;
  float* decoded = out;                 // [2048][32000] final log-softmax
  float* hiddens = out + 65536000L;     // [32][64][1024] final hiddens

  // Pre-logits scratch inside the decoded region (fully consumed before the
  // logits GEMM overwrites it).
  float* xg_e = decoded;                                    // 8,388,608 f
  float* xg_d = decoded + 8388608L;                         // 8,388,608 f
  unsigned short* xe_bf   = (unsigned short*)(decoded + 16777216L);  // 2,097,152 us
  unsigned short* ye_bf   = xe_bf + 2097152L;                        // 2,097,152 us
  unsigned short* WihE_bf = ye_bf + 2097152L;                        // 4,194,304 us
  unsigned short* WihD_bf = WihE_bf + 4194304L;                      // 4,194,304 us
  char* sp = (char*)(WihD_bf + 4194304L);
  unsigned short* hbuf = (unsigned short*)sp; sp += 2 * 32768 * 2;   // 16B-aligned
  float* hsel = (float*)sp; sp += 32768 * 4;
  float* csel = (float*)sp; sp += 32768 * 4;
  int* sel = (int*)sp; sp += 256;
  int* bar = (int*)sp; sp += 16384;  // 128 flags, 128B apart (zeroed by k_lengths)

  // ws: bf16 hiddens b-major (4MB) + bf16 Wout (65.5MB)
  unsigned short* hid_bf  = (unsigned short*)d_ws;
  unsigned short* Wout_bf = hid_bf + 2097152L;
  size_t need1 = 2048L * 1024 * 2;
  size_t need2 = need1 + 32000L * 1024 * 2;
  bool fast1 = ws_size >= need1;
  bool fast2 = ws_size >= need2;

  // gathers + lengths/bar-zero + Wih converts
  k_gather2<<<4096, 256, 0, stream>>>(embE, x, xe_bf, embC, y, ye_bf);
  k_lengths<<<1, 256, 0, stream>>>(xmask, sel, bar);
  k_f2bf_dual<<<2048, 256, 0, stream>>>(WihE, WihE_bf, WihD, WihD_bf, 1048576L);

  // both pre-gate GEMMs in one launch
  k_gemm_dual<<<1024, 256, 0, stream>>>(xe_bf, WihE_bf, bihE, xg_e,
                                        ye_bf, WihD_bf, bihD, xg_d);

  // encoder scan (+ Wout convert on spare CUs; spares retire, no deadlock risk)
  k_scan<0><<<SCAN_NBLK + (fast2 ? 112 : 0), 512, 0, stream>>>(
      WhhE, bhhE, xg_e, h0, c0, hbuf, sel, hsel, csel, nullptr, nullptr, bar,
      Wout, Wout_bf, fast2 ? 8192000L : 0L);
  // decoder scan
  k_scan<1><<<SCAN_NBLK, 512, 0, stream>>>(
      WhhD, bhhD, xg_d, hsel, csel, hbuf, nullptr, nullptr, nullptr, hiddens,
      fast1 ? hid_bf : nullptr, bar, nullptr, nullptr, 0L);

  // logits GEMM + log-softmax, in place in d_out
  if (fast2)      k_gemm_bb<<<4000, 256, 0, stream>>>(hid_bf, Wout_bf, bout, decoded);
  else if (fast1) k_gemm<unsigned short, float><<<4000, 256, 0, stream>>>(hid_bf, Wout, bout, decoded, 32000, 500);
  else            k_gemm<float, float><<<4000, 256, 0, stream>>>(hiddens, Wout, bout, decoded, 32000, 500);
  k_logsoftmax<<<2048, 256, 0, stream>>>(decoded);
}

// Round 12
// 888.906 us; speedup vs baseline: 1.1083x; 1.0239x over previous
//
#include <hip/hip_runtime.h>

typedef __attribute__((ext_vector_type(8))) short bf16x8;
typedef __attribute__((ext_vector_type(4))) float fx4;
typedef __attribute__((ext_vector_type(4))) unsigned short u16x4;
typedef __attribute__((ext_vector_type(8))) unsigned short u16x8;
typedef __attribute__((ext_vector_type(4))) unsigned int u32x4;

#define DEV static __device__ __forceinline__

DEV unsigned short f2bf(float f) {
  union { float f; unsigned u; } v; v.f = f;
  unsigned u = v.u;
  u += 0x7fffu + ((u >> 16) & 1u);
  return (unsigned short)(u >> 16);
}
DEV unsigned pk(float a, float b) { return (unsigned)f2bf(a) | ((unsigned)f2bf(b) << 16); }
DEV float sigm(float x) { return 1.f / (1.f + __expf(-x)); }

// coalesced 16B load bypassing (possibly stale) L1/L2, served at MALL.
DEV u32x4 load_coh16(const void* p) {
  u32x4 r;
  asm volatile("global_load_dwordx4 %0, %1, off sc0 sc1" : "=v"(r) : "v"(p));
  return r;
}

// async global->LDS 16B (m97 staging path)
typedef __attribute__((address_space(1))) const unsigned int guint;
typedef __attribute__((address_space(3))) unsigned int luint;
DEV void gload_lds16(const void* g, void* l) {
  __builtin_amdgcn_global_load_lds((guint*)g, (luint*)l, 16, 0, 0);
}

// ---------- dual embedding gather -> bf16, dst row r = t*32 + b ----------
__global__ void k_gather2(const float* __restrict__ embE, const int* __restrict__ tokE,
                          unsigned short* __restrict__ dstE,
                          const float* __restrict__ embC, const int* __restrict__ tokC,
                          unsigned short* __restrict__ dstC) {
  int bid = blockIdx.x;
  int r = bid & 2047;
  const float* emb = bid < 2048 ? embE : embC;
  const int* tok = bid < 2048 ? tokE : tokC;
  unsigned short* dst = bid < 2048 ? dstE : dstC;
  int t = r >> 5, b = r & 31;
  int token = tok[b * 64 + t];  // tok is [B=32][T=64]
  const fx4* srow = (const fx4*)(emb + (long)token * 1024);
  u16x4* drow = (u16x4*)(dst + (long)r * 1024);
  fx4 v = srow[threadIdx.x];
  u16x4 o = { f2bf(v[0]), f2bf(v[1]), f2bf(v[2]), f2bf(v[3]) };
  drow[threadIdx.x] = o;
}

// ---------- lengths + barrier zero ----------
__global__ void k_lengths(const int* __restrict__ mask, int* __restrict__ sel,
                          int* __restrict__ bar) {
  int t = threadIdx.x;
  for (int i = t; i < 4096; i += 256) bar[i] = 0;
  if (t < 32) {
    int s = 0;
    for (int k = 0; k < 64; ++k) s += mask[t * 64 + k];
    sel[t] = (s + 63) & 63;  // (sum-1) with jnp negative-index wrap
  }
}

// ---------- dual fp32 -> bf16 convert (WihE + WihD) ----------
__global__ void k_f2bf_dual(const float* __restrict__ s0, unsigned short* __restrict__ d0,
                            const float* __restrict__ s1, unsigned short* __restrict__ d1,
                            long n4) {
  const float* s = blockIdx.x < 1024 ? s0 : s1;
  unsigned short* d = blockIdx.x < 1024 ? d0 : d1;
  long base = (long)(blockIdx.x & 1023) * 256 + threadIdx.x;
  for (long i = base; i < n4; i += 1024 * 256) {
    fx4 v = ((const fx4*)s)[i];
    u16x4 o = { f2bf(v[0]), f2bf(v[1]), f2bf(v[2]), f2bf(v[3]) };
    ((u16x4*)d)[i] = o;
  }
}

// ============================================================================
// Persistent LSTM scan. 64 scan blocks x 512 threads, 1 block/CU (104 KB LDS).
// Block owns 16 j's (j0 XCD-swizzled: each XCD gets a contiguous 128-j band).
// 64 Whh rows (4 gates x 16 j) live in REGISTERS (32 x bf16x8 per wave).
// 8 waves = 2 batch-halves x 4 gate-tiles; each wave runs the FULL K=1024
// chain (no cross-wave k reduction). h staged to LDS via sc0/sc1 coalesced
// loads (4 MB/step MALL broadcast, half of the 128-block config).
// Barrier: 64 monotone flags 128B apart; wave0 polls ONE flag per lane.
// Enc gens 1..63, dec gens 65..127 (bar zeroed once in k_lengths).
// Blocks >=64 (MODE 0): Wout fp32->bf16 convert on idle CUs, then retire.
// ============================================================================
#define SCAN_NBLK 64

template<int MODE>  // 0 = encoder (save h,c at t==sel[b]); 1 = decoder (emit hiddens)
__global__ __launch_bounds__(512) void k_scan(
    const float* __restrict__ Whh,        // [4096][1024] fp32
    const float* __restrict__ bhh,        // [4096]
    const float* __restrict__ xg,         // [64][32][4096] fp32
    const float* __restrict__ hinit,      // [32][1024] fp32 (h0 or hsel)
    const float* __restrict__ cinit,      // [32][1024] fp32 (c0 or csel)
    unsigned short* __restrict__ hbuf,    // [2][32][1024] bf16 double buffer
    const int* __restrict__ sel,
    float* __restrict__ hsel, float* __restrict__ csel,
    float* __restrict__ hid_out,          // [32][64][1024] fp32 (decoder)
    unsigned short* __restrict__ hid_bf,  // [2048][1024] bf16 b-major (decoder)
    int* __restrict__ bar,
    const float* __restrict__ wsrc,       // MODE0: convert source
    unsigned short* __restrict__ wdst,    // MODE0: convert dest
    long wn4) {
  int tid = threadIdx.x;
  int bid = blockIdx.x;
  if (bid >= SCAN_NBLK) {  // spare blocks: Wout convert on idle CUs, then exit
    long i = (long)(bid - SCAN_NBLK) * 512 + tid;
    long st = (long)(gridDim.x - SCAN_NBLK) * 512;
    for (; i < wn4; i += st) {
      fx4 v = ((const fx4*)wsrc)[i];
      u16x4 o = { f2bf(v[0]), f2bf(v[1]), f2bf(v[2]), f2bf(v[3]) };
      ((u16x4*)wdst)[i] = o;
    }
    return;
  }
  __shared__ __align__(16) unsigned short hlds[49152];  // 96 KB decl (64 used)
  __shared__ float gbuf[4][32][16];                     // 8 KB
  int j0 = ((bid & 7) * 8 + (bid >> 3)) * 16;  // XCD-contiguous 128-j band
  int w = tid >> 6, lane = tid & 63;
  int mt = w & 1, nt = w >> 1;          // batch half (2) x gate tile (4)
  int fr = lane & 15, fg = lane >> 4;
  unsigned* hbU = (unsigned*)hbuf;
  constexpr int GBASE = MODE ? 64 : 0;

  // ---- one-time: this wave's Whh fragments into registers (fp32->bf16)
  // local row r = nt*16 + fr -> global Whh row nt*1024 + j0 + fr. 32 k-frags.
  bf16x8 breg[32];
  {
    const float* wrow = Whh + ((long)(nt * 1024 + j0 + fr) << 10);
#pragma unroll
    for (int i = 0; i < 32; ++i) {
      int kc = i * 4 + fg;
      fx4 lo = *(const fx4*)(wrow + kc * 8);
      fx4 hi = *(const fx4*)(wrow + kc * 8 + 4);
      bf16x8 o = { (short)f2bf(lo[0]), (short)f2bf(lo[1]), (short)f2bf(lo[2]), (short)f2bf(lo[3]),
                   (short)f2bf(hi[0]), (short)f2bf(hi[1]), (short)f2bf(hi[2]), (short)f2bf(hi[3]) };
      breg[i] = o;
    }
  }

  // ---- per-thread state: 512 threads = 32 b x 16 j ----
  int b = tid >> 4, jj = tid & 15, j = j0 + jj;
  float bh0 = bhh[j], bh1 = bhh[1024 + j], bh2 = bhh[2048 + j], bh3 = bhh[3072 + j];
  float c_reg = cinit[b * 1024 + j];
  int sel_b = (MODE == 0) ? sel[b] : -1;
  const float* xp0 = xg + (long)b * 4096 + j;
  float x0 = xp0[0], x1 = xp0[1024], x2 = xp0[2048], x3 = xp0[3072];

  for (int t = 0; t < 64; ++t) {
    // ---- stage h (64 KB bf16) into LDS, rows = b, 128 chunks of 16B ----
    if (t == 0) {
#pragma unroll
      for (int it = 0; it < 8; ++it) {
        int c = it * 512 + tid;
        const float* src = hinit + (long)c * 8;
        fx4 lo = *(const fx4*)src;
        fx4 hi = *(const fx4*)(src + 4);
        int row = c >> 7, kc = c & 127;
        u16x8 o = { f2bf(lo[0]), f2bf(lo[1]), f2bf(lo[2]), f2bf(lo[3]),
                    f2bf(hi[0]), f2bf(hi[1]), f2bf(hi[2]), f2bf(hi[3]) };
        *(u16x8*)&hlds[(row * 128 + (kc ^ (row & 31))) * 8] = o;
      }
    } else {
      const char* hsrc = (const char*)hbuf + (t & 1) * 65536;
      u32x4 hv[8];
#pragma unroll
      for (int it = 0; it < 8; ++it) {
        int c = it * 512 + tid;
        hv[it] = load_coh16(hsrc + (long)c * 16);
      }
      asm volatile("s_waitcnt vmcnt(0)" ::: "memory");
      __builtin_amdgcn_sched_barrier(0);
#pragma unroll
      for (int it = 0; it < 8; ++it) {
        int c = it * 512 + tid;
        int row = c >> 7, kc = c & 127;
        *(u16x8*)&hlds[(row * 128 + (kc ^ (row & 31))) * 8] = *(u16x8*)&hv[it];
      }
    }
    __syncthreads();

    // ---- gate GEMM: A-frags from hlds, B-frags from registers, full K ----
    int arow = mt * 16 + fr;
    fx4 acca = {0.f, 0.f, 0.f, 0.f}, accb = {0.f, 0.f, 0.f, 0.f};
#pragma unroll
    for (int i = 0; i < 32; i += 2) {
      int kcA = i * 4 + fg;
      int kcB = (i + 1) * 4 + fg;
      bf16x8 a0 = *(const bf16x8*)&hlds[(arow * 128 + (kcA ^ (arow & 31))) * 8];
      bf16x8 a1 = *(const bf16x8*)&hlds[(arow * 128 + (kcB ^ (arow & 31))) * 8];
      acca = __builtin_amdgcn_mfma_f32_16x16x32_bf16(a0, breg[i], acca, 0, 0, 0);
      accb = __builtin_amdgcn_mfma_f32_16x16x32_bf16(a1, breg[i + 1], accb, 0, 0, 0);
    }
#pragma unroll
    for (int q = 0; q < 4; ++q)
      gbuf[nt][mt * 16 + fg * 4 + q][fr] = acca[q] + accb[q];
    __syncthreads();

    // ---- gate nonlinearity + state update (all 512 threads: 32 b x 16 j) ----
    {
      float gi = gbuf[0][b][jj] + bh0 + x0;
      float gf = gbuf[1][b][jj] + bh1 + x1;
      float gg = gbuf[2][b][jj] + bh2 + x2;
      float go = gbuf[3][b][jj] + bh3 + x3;
      float c_new = sigm(gf) * c_reg + sigm(gi) * tanhf(gg);
      float h = sigm(go) * tanhf(c_new);
      c_reg = c_new;
      float hp = __shfl_xor(h, 1);
      if ((jj & 1) == 0) {
        unsigned val = pk(h, hp);
        __hip_atomic_store(&hbU[((t & 1) ^ 1) * 16384 + b * 512 + ((j0 + jj) >> 1)], val,
                           __ATOMIC_RELAXED, __HIP_MEMORY_SCOPE_AGENT);
      }
      if (MODE == 0) {
        if (t == sel_b) { hsel[b * 1024 + j] = h; csel[b * 1024 + j] = c_new; }
      } else {
        long o = ((long)b * 64 + t) * 1024 + j;
        hid_out[o] = h;
        if (hid_bf) hid_bf[o] = f2bf(h);  // plain store; read next kernel
      }
    }

    if (t < 63) {
      // prefetch next step's xg (latency hides under the barrier)
      const float* xp = xg + (long)(t + 1) * 131072 + (long)b * 4096 + j;
      float nx0 = xp[0], nx1 = xp[1024], nx2 = xp[2048], nx3 = xp[3072];
      __syncthreads();  // drains vmcnt -> this block's h stores are MALL-visible
      if (w == 0) {
        if (lane == 0)
          __hip_atomic_store(&bar[bid * 32], GBASE + t + 1, __ATOMIC_RELAXED, __HIP_MEMORY_SCOPE_AGENT);
        int want = GBASE + t + 1;
        for (;;) {
          int v0 = __hip_atomic_load(&bar[lane * 32], __ATOMIC_RELAXED, __HIP_MEMORY_SCOPE_AGENT);
          if (__ballot(v0 >= want) == 0xFFFFFFFFFFFFFFFFULL) break;
          __builtin_amdgcn_s_sleep(1);
        }
      }
      __syncthreads();
      x0 = nx0; x1 = nx1; x2 = nx2; x3 = nx3;
    }
  }
}

// ============================================================================
// Dual pre-gate GEMM (m97 + both-sides swizzle): blocks 0..511 -> set 0,
// 512..1023 -> set 1. (R7-R11 proven)
// ============================================================================
__global__ __launch_bounds__(256) void k_gemm_dual(
    const unsigned short* __restrict__ A0, const unsigned short* __restrict__ B0,
    const float* __restrict__ bias0, float* __restrict__ C0,
    const unsigned short* __restrict__ A1, const unsigned short* __restrict__ B1,
    const float* __restrict__ bias1, float* __restrict__ C1) {
  __shared__ __align__(16) unsigned short As[2][4096];
  __shared__ __align__(16) unsigned short Bs[2][4096];
  int lid = blockIdx.x;
  int half = lid >> 9, l = lid & 511;
  const unsigned short* A = half ? A1 : A0;
  const unsigned short* Bw = half ? B1 : B0;
  const float* bias = half ? bias1 : bias0;
  float* C = half ? C1 : C0;
  int swz = (l & 7) * 64 + (l >> 3);
  long m0 = (long)(swz & 15) * 128;
  long n0 = (long)(swz >> 4) * 128;
  int tid = threadIdx.x, lane = tid & 63, w = tid >> 6;
  int mw = (w & 1) * 64, nw = (w >> 1) * 64;
  int fr = lane & 15, fg = lane >> 4;
  fx4 acc[4][4] = {};
  int c0 = tid, c1 = tid + 256;
  int r0 = c0 >> 2, k0s = (c0 & 3) ^ ((r0 >> 1) & 3);
  int r1 = c1 >> 2, k1s = (c1 & 3) ^ ((r1 >> 1) & 3);
  const unsigned short* gA0 = A + (m0 + r0) * 1024 + k0s * 8;
  const unsigned short* gA1 = A + (m0 + r1) * 1024 + k1s * 8;
  const unsigned short* gB0 = Bw + (n0 + r0) * 1024 + k0s * 8;
  const unsigned short* gB1 = Bw + (n0 + r1) * 1024 + k1s * 8;
  auto stage = [&](int buf, int kt) {
    int k0 = kt * 32;
    gload_lds16(gA0 + k0, &As[buf][c0 * 8]);
    gload_lds16(gA1 + k0, &As[buf][c1 * 8]);
    gload_lds16(gB0 + k0, &Bs[buf][c0 * 8]);
    gload_lds16(gB1 + k0, &Bs[buf][c1 * 8]);
  };
  stage(0, 0);
  __syncthreads();
  for (int kt = 0; kt < 32; ++kt) {
    int cur = kt & 1;
    if (kt < 31) stage(cur ^ 1, kt + 1);
    bf16x8 af[4], bfr[4];
#pragma unroll
    for (int mi = 0; mi < 4; ++mi) {
      int row = mw + mi * 16 + fr;
      af[mi] = *(const bf16x8*)&As[cur][(row * 4 + (fg ^ ((row >> 1) & 3))) * 8];
    }
#pragma unroll
    for (int ni = 0; ni < 4; ++ni) {
      int row = nw + ni * 16 + fr;
      bfr[ni] = *(const bf16x8*)&Bs[cur][(row * 4 + (fg ^ ((row >> 1) & 3))) * 8];
    }
#pragma unroll
    for (int mi = 0; mi < 4; ++mi)
#pragma unroll
      for (int ni = 0; ni < 4; ++ni)
        acc[mi][ni] = __builtin_amdgcn_mfma_f32_16x16x32_bf16(af[mi], bfr[ni], acc[mi][ni], 0, 0, 0);
    __syncthreads();
  }
#pragma unroll
  for (int ni = 0; ni < 4; ++ni) {
    long n = n0 + nw + ni * 16 + fr;
    float bs = bias[n];
#pragma unroll
    for (int mi = 0; mi < 4; ++mi) {
      long rbase = m0 + mw + mi * 16 + fg * 4;
#pragma unroll
      for (int q = 0; q < 4; ++q)
        C[(rbase + q) * 4096 + n] = acc[mi][ni][q] + bs;
    }
  }
}

// ============================================================================
// Logits GEMM (m97 + both-sides swizzle, no epilogue extras — R11 proven).
// M=2048 N=32000 K=1024, grid 4000, q8=500.
// ============================================================================
__global__ __launch_bounds__(256) void k_gemm_bb(const unsigned short* __restrict__ A,
                                                 const unsigned short* __restrict__ Bw,
                                                 const float* __restrict__ bias,
                                                 float* __restrict__ C) {
  __shared__ __align__(16) unsigned short As[2][4096];
  __shared__ __align__(16) unsigned short Bs[2][4096];
  int lid = blockIdx.x;
  int swz = (lid & 7) * 500 + (lid >> 3);   // XCD-chunked (4000 % 8 == 0)
  long m0 = (long)(swz & 15) * 128;         // m inner -> B-panel L2 reuse
  long n0 = (long)(swz >> 4) * 128;
  int tid = threadIdx.x, lane = tid & 63, w = tid >> 6;
  int mw = (w & 1) * 64, nw = (w >> 1) * 64;
  int fr = lane & 15, fg = lane >> 4;
  fx4 acc[4][4] = {};
  int c0 = tid, c1 = tid + 256;
  int r0 = c0 >> 2, k0s = (c0 & 3) ^ ((r0 >> 1) & 3);
  int r1 = c1 >> 2, k1s = (c1 & 3) ^ ((r1 >> 1) & 3);
  const unsigned short* gA0 = A + (m0 + r0) * 1024 + k0s * 8;
  const unsigned short* gA1 = A + (m0 + r1) * 1024 + k1s * 8;
  const unsigned short* gB0 = Bw + (n0 + r0) * 1024 + k0s * 8;
  const unsigned short* gB1 = Bw + (n0 + r1) * 1024 + k1s * 8;
  auto stage = [&](int buf, int kt) {
    int k0 = kt * 32;
    gload_lds16(gA0 + k0, &As[buf][c0 * 8]);
    gload_lds16(gA1 + k0, &As[buf][c1 * 8]);
    gload_lds16(gB0 + k0, &Bs[buf][c0 * 8]);
    gload_lds16(gB1 + k0, &Bs[buf][c1 * 8]);
  };
  stage(0, 0);
  __syncthreads();
  for (int kt = 0; kt < 32; ++kt) {
    int cur = kt & 1;
    if (kt < 31) stage(cur ^ 1, kt + 1);
    bf16x8 af[4], bfr[4];
#pragma unroll
    for (int mi = 0; mi < 4; ++mi) {
      int row = mw + mi * 16 + fr;
      af[mi] = *(const bf16x8*)&As[cur][(row * 4 + (fg ^ ((row >> 1) & 3))) * 8];
    }
#pragma unroll
    for (int ni = 0; ni < 4; ++ni) {
      int row = nw + ni * 16 + fr;
      bfr[ni] = *(const bf16x8*)&Bs[cur][(row * 4 + (fg ^ ((row >> 1) & 3))) * 8];
    }
#pragma unroll
    for (int mi = 0; mi < 4; ++mi)
#pragma unroll
      for (int ni = 0; ni < 4; ++ni)
        acc[mi][ni] = __builtin_amdgcn_mfma_f32_16x16x32_bf16(af[mi], bfr[ni], acc[mi][ni], 0, 0, 0);
    __syncthreads();
  }
#pragma unroll
  for (int ni = 0; ni < 4; ++ni) {
    long n = n0 + nw + ni * 16 + fr;
    float bs = bias[n];
#pragma unroll
    for (int mi = 0; mi < 4; ++mi) {
      long rbase = m0 + mw + mi * 16 + fg * 4;
#pragma unroll
      for (int q = 0; q < 4; ++q)
        C[(rbase + q) * 32000 + n] = acc[mi][ni][q] + bs;
    }
  }
}

// ============================================================================
// Fallback GEMM (reg-staged, B may be fp32 converted in-register).
// ============================================================================
template<typename TA, typename TB>
__global__ __launch_bounds__(256) void k_gemm(const TA* __restrict__ A,
                                              const TB* __restrict__ Bw,
                                              const float* __restrict__ bias,
                                              float* __restrict__ C,
                                              int ldc, int q8) {
  __shared__ __align__(16) unsigned short As[2][4096];
  __shared__ __align__(16) unsigned short Bs[2][4096];
  int lid = blockIdx.x;
  int swz = (lid & 7) * q8 + (lid >> 3);
  long m0 = (long)(swz & 15) * 128;
  long n0 = (long)(swz >> 4) * 128;
  int tid = threadIdx.x, lane = tid & 63, w = tid >> 6;
  int mw = (w & 1) * 64, nw = (w >> 1) * 64;
  int fr = lane & 15, fg = lane >> 4;
  fx4 acc[4][4] = {};

  int crow[2], kc[2], phys[2];
#pragma unroll
  for (int u = 0; u < 2; ++u) {
    int c = tid + u * 256;
    crow[u] = c >> 2; kc[u] = c & 3;
    phys[u] = crow[u] * 4 + (kc[u] ^ ((crow[u] >> 1) & 3));
  }
  u32x4 ra[2], rb[2];
  auto loadOne = [&](const auto* P, long row, int u) -> u32x4 {
    long off = row * 1024 + kc[u] * 8;
    if constexpr (sizeof(*P) == 2) {
      return *(const u32x4*)(P + off);
    } else {
      fx4 lo = *(const fx4*)(P + off);
      fx4 hi = *(const fx4*)(P + off + 4);
      u32x4 r = { pk(lo[0], lo[1]), pk(lo[2], lo[3]), pk(hi[0], hi[1]), pk(hi[2], hi[3]) };
      return r;
    }
  };
  auto loadRegs = [&](int kt) {
#pragma unroll
    for (int u = 0; u < 2; ++u) {
      ra[u] = loadOne(A + (long)kt * 32, m0 + crow[u], u);
      rb[u] = loadOne(Bw + (long)kt * 32, n0 + crow[u], u);
    }
  };
  auto storeRegs = [&](int buf) {
#pragma unroll
    for (int u = 0; u < 2; ++u) {
      *(u32x4*)&As[buf][phys[u] * 8] = ra[u];
      *(u32x4*)&Bs[buf][phys[u] * 8] = rb[u];
    }
  };
  loadRegs(0);
  storeRegs(0);
  __syncthreads();
  for (int kt = 0; kt < 32; ++kt) {
    int cur = kt & 1;
    if (kt < 31) loadRegs(kt + 1);
    bf16x8 af[4], bf_[4];
#pragma unroll
    for (int mi = 0; mi < 4; ++mi) {
      int row = mw + mi * 16 + fr;
      af[mi] = *(const bf16x8*)&As[cur][(row * 4 + (fg ^ ((row >> 1) & 3))) * 8];
    }
#pragma unroll
    for (int ni = 0; ni < 4; ++ni) {
      int row = nw + ni * 16 + fr;
      bf_[ni] = *(const bf16x8*)&Bs[cur][(row * 4 + (fg ^ ((row >> 1) & 3))) * 8];
    }
#pragma unroll
    for (int mi = 0; mi < 4; ++mi)
#pragma unroll
      for (int ni = 0; ni < 4; ++ni)
        acc[mi][ni] = __builtin_amdgcn_mfma_f32_16x16x32_bf16(af[mi], bf_[ni], acc[mi][ni], 0, 0, 0);
    if (kt < 31) storeRegs((kt + 1) & 1);
    __syncthreads();
  }
#pragma unroll
  for (int ni = 0; ni < 4; ++ni) {
    long n = n0 + nw + ni * 16 + fr;
    float bs = bias[n];
#pragma unroll
    for (int mi = 0; mi < 4; ++mi) {
      long rbase = m0 + mw + mi * 16 + fg * 4;
#pragma unroll
      for (int q = 0; q < 4; ++q)
        C[(rbase + q) * ldc + n] = acc[mi][ni][q] + bs;
    }
  }
}

// ---------- in-place row log-softmax, online max+sum (single extra read) ----------
__global__ __launch_bounds__(256) void k_logsoftmax(float* __restrict__ logits) {
  long base = (long)blockIdx.x * 32000;
  float* row = logits + base;
  int tid = threadIdx.x;
  __shared__ float redm[4], reds[4];
  float m = -3.4e38f, s = 0.f;
  for (int i = tid; i < 8000; i += 256) {
    fx4 v = ((const fx4*)row)[i];
    float cm = fmaxf(fmaxf(v[0], v[1]), fmaxf(v[2], v[3]));
    if (cm > m) { s *= __expf(m - cm); m = cm; }
    s += __expf(v[0] - m) + __expf(v[1] - m) + __expf(v[2] - m) + __expf(v[3] - m);
  }
  for (int o = 32; o; o >>= 1) {
    float m2 = __shfl_xor(m, o), s2 = __shfl_xor(s, o);
    float mn = fmaxf(m, m2);
    s = s * __expf(m - mn) + s2 * __expf(m2 - mn);
    m = mn;
  }
  if ((tid & 63) == 0) { redm[tid >> 6] = m; reds[tid >> 6] = s; }
  __syncthreads();
  float M = fmaxf(fmaxf(redm[0], redm[1]), fmaxf(redm[2], redm[3]));
  float S = reds[0] * __expf(redm[0] - M) + reds[1] * __expf(redm[1] - M) +
            reds[2] * __expf(redm[2] - M) + reds[3] * __expf(redm[3] - M);
  float lse = M + logf(S);
  for (int i = tid; i < 8000; i += 256) {
    fx4 v = ((const fx4*)row)[i];
    fx4 o = { v[0] - lse, v[1] - lse, v[2] - lse, v[3] - lse };
    ((fx4*)row)[i] = o;
  }
}

extern "C" void kernel_launch(void* const* d_in, const int* in_sizes, int n_in,
                              void* d_out, int out_size, void* d_ws, size_t ws_size,
                              hipStream_t stream) {
  const int*   x     = (const int*)d_in[0];
  const int*   xmask = (const int*)d_in[1];
  const int*   y     = (const int*)d_in[2];
  const float* h0    = (const float*)d_in[3];
  const float* c0    = (const float*)d_in[4];
  const float* embE  = (const float*)d_in[5];
  const float* embC  = (const float*)d_in[6];
  const float* WihE  = (const float*)d_in[7];
  const float* WhhE  = (const float*)d_in[8];
  const float* bihE  = (const float*)d_in[9];
  const float* bhhE  = (const float*)d_in[10];
  const float* WihD  = (const float*)d_in[11];
  const float* WhhD  = (const float*)d_in[12];
  const float* bihD  = (const float*)d_in[13];
  const float* bhhD  = (const float*)d_in[14];
  const float* Wout  = (const float*)d_in[15];
  const float* bout  = (const float*)d_in[16];

  float* out = (float*)d_out;
  float* decoded = out;                 // [2048][32000] final log-softmax
  float* hiddens = out + 65536000L;     // [32][64][1024] final hiddens

  // Pre-logits scratch inside the decoded region (fully consumed before the
  // logits GEMM overwrites it).
  float* xg_e = decoded;                                    // 8,388,608 f
  float* xg_d = decoded + 8388608L;                         // 8,388,608 f
  unsigned short* xe_bf   = (unsigned short*)(decoded + 16777216L);  // 2,097,152 us
  unsigned short* ye_bf   = xe_bf + 2097152L;                        // 2,097,152 us
  unsigned short* WihE_bf = ye_bf + 2097152L;                        // 4,194,304 us
  unsigned short* WihD_bf = WihE_bf + 4194304L;                      // 4,194,304 us
  char* sp = (char*)(WihD_bf + 4194304L);
  unsigned short* hbuf = (unsigned short*)sp; sp += 2 * 32768 * 2;   // 16B-aligned
  float* hsel = (float*)sp; sp += 32768 * 4;
  float* csel = (float*)sp; sp += 32768 * 4;
  int* sel = (int*)sp; sp += 256;
  int* bar = (int*)sp; sp += 16384;  // 64 flags, 128B apart (zeroed by k_lengths)

  // ws: bf16 hiddens b-major (4MB) + bf16 Wout (65.5MB)
  unsigned short* hid_bf  = (unsigned short*)d_ws;
  unsigned short* Wout_bf = hid_bf + 2097152L;
  size_t need1 = 2048L * 1024 * 2;
  size_t need2 = need1 + 32000L * 1024 * 2;
  bool fast1 = ws_size >= need1;
  bool fast2 = ws_size >= need2;

  // gathers + lengths/bar-zero + Wih converts
  k_gather2<<<4096, 256, 0, stream>>>(embE, x, xe_bf, embC, y, ye_bf);
  k_lengths<<<1, 256, 0, stream>>>(xmask, sel, bar);
  k_f2bf_dual<<<2048, 256, 0, stream>>>(WihE, WihE_bf, WihD, WihD_bf, 1048576L);

  // both pre-gate GEMMs in one launch
  k_gemm_dual<<<1024, 256, 0, stream>>>(xe_bf, WihE_bf, bihE, xg_e,
                                        ye_bf, WihD_bf, bihD, xg_d);

  // encoder scan (+ Wout convert on spare CUs; spares retire, no deadlock risk)
  k_scan<0><<<SCAN_NBLK + (fast2 ? 192 : 0), 512, 0, stream>>>(
      WhhE, bhhE, xg_e, h0, c0, hbuf, sel, hsel, csel, nullptr, nullptr, bar,
      Wout, Wout_bf, fast2 ? 8192000L : 0L);
  // decoder scan
  k_scan<1><<<SCAN_NBLK, 512, 0, stream>>>(
      WhhD, bhhD, xg_d, hsel, csel, hbuf, nullptr, nullptr, nullptr, hiddens,
      fast1 ? hid_bf : nullptr, bar, nullptr, nullptr, 0L);

  // logits GEMM + log-softmax, in place in d_out
  if (fast2)      k_gemm_bb<<<4000, 256, 0, stream>>>(hid_bf, Wout_bf, bout, decoded);
  else if (fast1) k_gemm<unsigned short, float><<<4000, 256, 0, stream>>>(hid_bf, Wout, bout, decoded, 32000, 500);
  else            k_gemm<float, float><<<4000, 256, 0, stream>>>(hiddens, Wout, bout, decoded, 32000, 500);
  k_logsoftmax<<<2048, 256, 0, stream>>>(decoded);
}